// Round 3
// baseline (96.718 us; speedup 1.0000x reference)
//
#include <hip/hip_runtime.h>
#include <hip/hip_bf16.h>

#define N 8192
#define D 128
#define HALF_N 4096
// z pre-scaled by sqrt(10 * log2(e)) so acc = z.z^T is sim in log2 domain:
// exp(sim) == exp2(acc). pos (= sim) recovered as acc * ln2 on its single tile.
#define SQRT_SCALE_LOG2E 3.79828236f
#define LN2 0.693147180559945f

#define BLOCK_ROWS 256   // 4 waves * 64 rows each
#define COL_SPLITS 16
#define COLS_PER_BLOCK (N / COL_SPLITS)          // 512
#define SUBTILES (COLS_PER_BLOCK / 16)           // 32 subtiles of 16 cols

typedef short frag8 __attribute__((ext_vector_type(8)));
typedef float f32x4 __attribute__((ext_vector_type(4)));

// ws layout (floats): pos[N] | psums[COL_SPLITS][N] | acc0 | pad | z (bf16)
#define OFF_POS    0
#define OFF_PSUMS  (N)
#define OFF_ACC    (N + COL_SPLITS * N)
#define OFF_Z_BYTES ((OFF_ACC + 64) * 4)

__device__ __forceinline__ unsigned short f2bf(float f) {
    unsigned int u = __float_as_uint(f);
    u += 0x7FFFu + ((u >> 16) & 1u);
    return (unsigned short)(u >> 16);
}

// K1: z = sqrt(10*log2e) * x / max(||x||, eps)  (bf16); zero scalar acc.
__global__ __launch_bounds__(256) void k_normalize(const float* __restrict__ x,
                                                   unsigned short* __restrict__ z,
                                                   float* __restrict__ acc0) {
    const int row  = blockIdx.x * 4 + (threadIdx.x >> 6);
    const int lane = threadIdx.x & 63;
    float2 v = ((const float2*)x)[row * 64 + lane];
    float s = v.x * v.x + v.y * v.y;
    #pragma unroll
    for (int m = 32; m >= 1; m >>= 1) s += __shfl_xor(s, m);
    float inv = SQRT_SCALE_LOG2E / fmaxf(sqrtf(s), 1e-8f);
    ushort2 o;
    o.x = f2bf(v.x * inv);
    o.y = f2bf(v.y * inv);
    ((ushort2*)z)[row * 64 + lane] = o;
    if (blockIdx.x == 0 && threadIdx.x == 0) acc0[0] = 0.0f;
}

// K2: fused z.z^T + exp2 + per-row partial sums.
// v3: NO LDS, NO barriers. z is 2 MB -> L2-resident on every XCD; LDS staging
// saved no traffic (all 4 waves read the whole B-tile anyway) and cost
// 2 barriers+vmcnt-drain per iter (round-2 post-mortem: k_simloss ~34us vs
// ~12us floor). Each wave now streams B-fragments straight from L2 with a
// depth-2 register double-buffer; waves are fully independent.
__global__ __launch_bounds__(256, 2) void k_simloss(const unsigned short* __restrict__ z,
                                                    float* __restrict__ psums,
                                                    float* __restrict__ pos) {
    const int tid  = threadIdx.x;
    const int wave = tid >> 6;
    const int lane = tid & 63;
    const int l15  = lane & 15;
    const int quad = lane >> 4;
    const int wrow = blockIdx.x * BLOCK_ROWS + wave * 64;
    const int colbase0 = blockIdx.y * COLS_PER_BLOCK;
    const int posbase  = (wrow + HALF_N) & (N - 1);

    // A fragments: 4 row-stripes of 16 x K=128, register-resident (64 VGPRs).
    frag8 a[4][4];
    #pragma unroll
    for (int s = 0; s < 4; ++s) {
        const uint4* p = (const uint4*)&z[(wrow + s * 16 + l15) * D + quad * 8];
        #pragma unroll
        for (int q = 0; q < 4; ++q) {
            uint4 t = p[q * 4];
            a[s][q] = *(frag8*)&t;
        }
    }

    float sums[4][4];
    #pragma unroll
    for (int s = 0; s < 4; ++s)
        #pragma unroll
        for (int r = 0; r < 4; ++r) sums[s][r] = 0.0f;

    // Per-lane B base: lane (quad,l15) reads B[col0+l15][quad*8 + q*32 .. +8].
    // 4 lanes (quad 0..3, same l15) cover a contiguous 64 B segment -> coalesced.
    const unsigned short* zlane = z + l15 * D + quad * 8;

    auto load_b = [&](frag8 (&b)[4], int t) {
        const unsigned short* bp = zlane + (colbase0 + t * 16) * D;
        #pragma unroll
        for (int q = 0; q < 4; ++q)
            b[q] = *(const frag8*)(bp + q * 32);
    };

    auto compute_tile = [&](int t, frag8 (&b)[4]) {
        f32x4 acc[4];
        #pragma unroll
        for (int s = 0; s < 4; ++s) acc[s] = (f32x4){0.f, 0.f, 0.f, 0.f};
        #pragma unroll
        for (int q = 0; q < 4; ++q)
            #pragma unroll
            for (int s = 0; s < 4; ++s)
                acc[s] = __builtin_amdgcn_mfma_f32_16x16x32_bf16(a[s][q], b[q], acc[s], 0, 0, 0);

        const int col0 = colbase0 + t * 16;
        const unsigned dd = (unsigned)(col0 - wrow);
        const unsigned pp = (unsigned)(col0 - posbase);
        if ((dd < 64u) | (pp < 64u)) {
            // subtile may contain diagonal and/or positive-pair elements
            #pragma unroll
            for (int s = 0; s < 4; ++s) {
                const bool d = (col0 == wrow + s * 16);
                const bool p = (col0 == posbase + s * 16);
                #pragma unroll
                for (int r = 0; r < 4; ++r) {
                    float v = acc[s][r];
                    float e = __builtin_amdgcn_exp2f(v);
                    if (d | p) {
                        bool hit = (l15 == quad * 4 + r);
                        if (d && hit) e = 0.0f;
                        if (p && hit) pos[wrow + s * 16 + quad * 4 + r] = v * LN2;
                    }
                    sums[s][r] += e;
                }
            }
        } else {
            #pragma unroll
            for (int s = 0; s < 4; ++s)
                #pragma unroll
                for (int r = 0; r < 4; ++r)
                    sums[s][r] += __builtin_amdgcn_exp2f(acc[s][r]);
        }
    };

    // Depth-2 software pipeline over 32 subtiles; named buffers (static
    // indexing, rule #20), outer loop NOT unrolled so the compiler can't
    // hoist all 128 loads and blow the VGPR budget (round-1 lesson).
    frag8 b0[4], b1[4];
    load_b(b0, 0);
    #pragma unroll 1
    for (int t = 0; t < SUBTILES; t += 2) {
        load_b(b1, t + 1);
        compute_tile(t, b0);
        load_b(b0, t + 2);   // t=30 -> reads 16B/lane past z inside ws; unused
        compute_tile(t + 1, b1);
    }

    // Reduce each row-sum across the 16 lanes holding that row; one store per row.
    #pragma unroll
    for (int s = 0; s < 4; ++s)
        #pragma unroll
        for (int r = 0; r < 4; ++r) {
            float v = sums[s][r];
            v += __shfl_xor(v, 1);
            v += __shfl_xor(v, 2);
            v += __shfl_xor(v, 4);
            v += __shfl_xor(v, 8);
            if (l15 == 0)
                psums[blockIdx.y * N + wrow + s * 16 + quad * 4 + r] = v;
        }
}

// K3a: per-row loss = log(sum of partials) - pos; block-reduce; atomic into acc0.
__global__ __launch_bounds__(1024) void k_rowloss(const float* __restrict__ psums,
                                                  const float* __restrict__ pos,
                                                  float* __restrict__ acc0) {
    const int row = blockIdx.x * 1024 + threadIdx.x;
    float t = 0.0f;
    #pragma unroll
    for (int s = 0; s < COL_SPLITS; ++s) t += psums[s * N + row];
    float loss = __logf(t) - pos[row];
    #pragma unroll
    for (int m = 32; m >= 1; m >>= 1) loss += __shfl_xor(loss, m);
    __shared__ float p[16];
    if ((threadIdx.x & 63) == 0) p[threadIdx.x >> 6] = loss;
    __syncthreads();
    if (threadIdx.x == 0) {
        float s = 0.0f;
        #pragma unroll
        for (int w = 0; w < 16; ++w) s += p[w];
        atomicAdd(acc0, s);
    }
}

// K3b: mean.
__global__ void k_final(const float* __restrict__ acc0, float* __restrict__ out) {
    out[0] = acc0[0] * (1.0f / N);
}

extern "C" void kernel_launch(void* const* d_in, const int* in_sizes, int n_in,
                              void* d_out, int out_size, void* d_ws, size_t ws_size,
                              hipStream_t stream) {
    const float* x = (const float*)d_in[0];
    float* wsf   = (float*)d_ws;
    float* pos   = wsf + OFF_POS;
    float* psums = wsf + OFF_PSUMS;
    float* acc0  = wsf + OFF_ACC;
    unsigned short* z = (unsigned short*)((char*)d_ws + OFF_Z_BYTES);

    k_normalize<<<N / 4, 256, 0, stream>>>(x, z, acc0);
    dim3 g2(N / BLOCK_ROWS, COL_SPLITS);  // (32, 16) = 512 blocks -> 2/CU
    k_simloss<<<g2, 256, 0, stream>>>(z, psums, pos);
    k_rowloss<<<N / 1024, 1024, 0, stream>>>(psums, pos, acc0);
    k_final<<<1, 1, 0, stream>>>(acc0, (float*)d_out);
}

// Round 4
// 87.568 us; speedup vs baseline: 1.1045x; 1.1045x over previous
//
#include <hip/hip_runtime.h>
#include <hip/hip_bf16.h>

#define N 8192
#define D 128
#define HALF_N 4096
// z pre-scaled by sqrt(10 * log2(e)) so acc = z.z^T is sim in log2 domain:
// exp(sim) == exp2(acc). pos (= sim) recovered as acc * ln2 on its single tile.
#define SQRT_SCALE_LOG2E 3.79828236f
#define LN2 0.693147180559945f

#define BLOCK_ROWS 256   // 4 waves * 64 rows each
#define COLS_PER_ITER 64
#define COL_SPLITS 16
#define COLS_PER_BLOCK (N / COL_SPLITS)          // 512
#define ITERS (COLS_PER_BLOCK / COLS_PER_ITER)   // 8
#define NBUF 4           // 4-deep LDS ring: leading wave's stage(t+3) vs
                         // trailing wave's compute(t) -> needs mod-4 (mod-3 races)

typedef short frag8 __attribute__((ext_vector_type(8)));
typedef float f32x16 __attribute__((ext_vector_type(16)));
typedef const __attribute__((address_space(1))) unsigned int* gbl_u32p;
typedef __attribute__((address_space(3))) unsigned int* lds_u32p;

// ws layout (floats): pos[N] | psums[COL_SPLITS][N] | acc0 | pad | z (bf16)
#define OFF_POS    0
#define OFF_PSUMS  (N)
#define OFF_ACC    (N + COL_SPLITS * N)
#define OFF_Z_BYTES ((OFF_ACC + 64) * 4)

__device__ __forceinline__ unsigned short f2bf(float f) {
    unsigned int u = __float_as_uint(f);
    u += 0x7FFFu + ((u >> 16) & 1u);
    return (unsigned short)(u >> 16);
}

// K1: z = sqrt(10*log2e) * x / max(||x||, eps)  (bf16); zero scalar acc.
__global__ __launch_bounds__(256) void k_normalize(const float* __restrict__ x,
                                                   unsigned short* __restrict__ z,
                                                   float* __restrict__ acc0) {
    const int row  = blockIdx.x * 4 + (threadIdx.x >> 6);
    const int lane = threadIdx.x & 63;
    float2 v = ((const float2*)x)[row * 64 + lane];
    float s = v.x * v.x + v.y * v.y;
    #pragma unroll
    for (int m = 32; m >= 1; m >>= 1) s += __shfl_xor(s, m);
    float inv = SQRT_SCALE_LOG2E / fmaxf(sqrtf(s), 1e-8f);
    ushort2 o;
    o.x = f2bf(v.x * inv);
    o.y = f2bf(v.y * inv);
    ((ushort2*)z)[row * 64 + lane] = o;
    if (blockIdx.x == 0 && threadIdx.x == 0) acc0[0] = 0.0f;
}

// Stage one 64x128 bf16 tile into LDS via global_load_lds (linear dest,
// XOR-swizzled source so the ds_read side can swizzle conflict-free).
__device__ __forceinline__ void stage_tile(const unsigned short* __restrict__ z,
                                           unsigned short* ldsbuf,
                                           int colbase, int wave,
                                           const int* stg_src) {
    const unsigned short* zc = z + (size_t)colbase * D;
    #pragma unroll
    for (int u = 0; u < 4; ++u) {
        // wave-uniform LDS base; HW writes base + lane*16B (row = +lane>>4, chunk = lane&15)
        __builtin_amdgcn_global_load_lds((gbl_u32p)(zc + stg_src[u]),
                                         (lds_u32p)(ldsbuf + (wave * 16 + u * 4) * D),
                                         16, 0, 0);
    }
}

// K2: fused z.z^T + exp2 + per-row partial sums.
// v4: round-2 LDS structure (beat no-LDS) + 32x32x16 MFMA (-20% matrix cycles,
// -50% MFMA insts, 2 long dep-chains) + counted-vmcnt 4-buffer pipeline
// (T3/T4-lite: stage t+2 in flight, never drain vmcnt to 0 in the loop).
__global__ __launch_bounds__(256, 2) void k_simloss(const unsigned short* __restrict__ z,
                                                    float* __restrict__ psums,
                                                    float* __restrict__ pos) {
    __shared__ unsigned short lds[NBUF][COLS_PER_ITER * D];  // 4 x 16 KB = 64 KB

    const int tid  = threadIdx.x;
    const int wave = tid >> 6;
    const int lane = tid & 63;
    const int c31  = lane & 31;
    const int hi   = lane >> 5;
    const int wrow = blockIdx.x * BLOCK_ROWS + wave * 64;
    const int colbase0 = blockIdx.y * COLS_PER_BLOCK;
    const int posbase  = (wrow + HALF_N) & (N - 1);

    // Staging source offsets: LDS slot (r, chunk'=l15) holds global chunk (l15 ^ (r&7)).
    int stg_src[4];
    #pragma unroll
    for (int u = 0; u < 4; ++u) {
        int r = wave * 16 + u * 4 + (lane >> 4);
        stg_src[u] = r * D + (((lane & 15) ^ (r & 7)) << 3);
    }

    // A fragments for 32x32x16: 2 stripes of 32 rows; lane holds
    // A[row = wrow + s*32 + (lane&31)][k = kc*16 + hi*8 + j], j=0..7. 64 VGPRs.
    frag8 a[2][8];
    #pragma unroll
    for (int s = 0; s < 2; ++s) {
        const unsigned short* ap = &z[(wrow + s * 32 + c31) * D + hi * 8];
        #pragma unroll
        for (int kc = 0; kc < 8; ++kc)
            a[s][kc] = *(const frag8*)(ap + kc * 16);
    }
    // Pin A-load issue before stage(0)/stage(1): the loop's vmcnt(8) arithmetic
    // relies on all A-loads + stage(t) being older than the two newest stages.
    asm volatile("" ::: "memory");

    float sums[2][16];
    #pragma unroll
    for (int s = 0; s < 2; ++s)
        #pragma unroll
        for (int r = 0; r < 16; ++r) sums[s][r] = 0.0f;

    stage_tile(z, &lds[0][0], colbase0 + 0 * COLS_PER_ITER, wave, stg_src);
    stage_tile(z, &lds[1][0], colbase0 + 1 * COLS_PER_ITER, wave, stg_src);

    #pragma unroll 1
    for (int t = 0; t < ITERS; ++t) {
        // vmcnt(8) = "everything except the two newest stages (t+1, t+2) has
        // landed" -> tile t ready in this wave; barrier makes it true for all
        // waves (each wave drained its own share before arriving).
        if (t + 2 < ITERS) {
            stage_tile(z, &lds[(t + 2) & 3][0], colbase0 + (t + 2) * COLS_PER_ITER, wave, stg_src);
            asm volatile("s_waitcnt vmcnt(8)" ::: "memory");
        } else if (t + 2 == ITERS) {
            asm volatile("s_waitcnt vmcnt(4)" ::: "memory");
        } else {
            asm volatile("s_waitcnt vmcnt(0)" ::: "memory");
        }
        __builtin_amdgcn_s_barrier();
        asm volatile("" ::: "memory");  // no ds_read hoisting above the barrier

        const unsigned short* lb = &lds[t & 3][0];
        const int colbase = colbase0 + t * COLS_PER_ITER;

        #pragma unroll
        for (int ct = 0; ct < 2; ++ct) {
            const int col0 = colbase + ct * 32;
            f32x16 acc0, acc1;
            #pragma unroll
            for (int i = 0; i < 16; ++i) { acc0[i] = 0.0f; acc1[i] = 0.0f; }

            // B frag: col = ct*32 + (lane&31), data k-chunk (kc*2+hi) stored at
            // physical slot (kc*2+hi)^(col&7). 8 accesses/bank = wave b128 floor.
            #pragma unroll
            for (int kc = 0; kc < 8; ++kc) {
                frag8 b = *(const frag8*)&lb[(ct * 32 + c31) * D +
                                             (((kc * 2 + hi) ^ (c31 & 7)) << 3)];
                acc0 = __builtin_amdgcn_mfma_f32_32x32x16_bf16(a[0][kc], b, acc0, 0, 0, 0);
                acc1 = __builtin_amdgcn_mfma_f32_32x32x16_bf16(a[1][kc], b, acc1, 0, 0, 0);
            }

            // C/D: col = lane&31, row = (r&3) + 8*(r>>2) + 4*hi  (m74/m101)
            const bool d0 = (col0 == wrow);
            const bool d1 = (col0 == wrow + 32);
            const bool p0 = (col0 == posbase);
            const bool p1 = (col0 == posbase + 32);
            if (d0 | d1 | p0 | p1) {
                #pragma unroll
                for (int r = 0; r < 16; ++r) {
                    const int rowoff = (r & 3) + 8 * (r >> 2) + 4 * hi;
                    const bool hit = (c31 == rowoff);
                    {
                        float v = acc0[r];
                        float e = __builtin_amdgcn_exp2f(v);
                        if (d0 && hit) e = 0.0f;
                        if (p0 && hit) pos[wrow + rowoff] = v * LN2;
                        sums[0][r] += e;
                    }
                    {
                        float v = acc1[r];
                        float e = __builtin_amdgcn_exp2f(v);
                        if (d1 && hit) e = 0.0f;
                        if (p1 && hit) pos[wrow + 32 + rowoff] = v * LN2;
                        sums[1][r] += e;
                    }
                }
            } else {
                #pragma unroll
                for (int r = 0; r < 16; ++r) {
                    sums[0][r] += __builtin_amdgcn_exp2f(acc0[r]);
                    sums[1][r] += __builtin_amdgcn_exp2f(acc1[r]);
                }
            }
        }
    }

    // Row-sum: reduce across the 32 col-lanes of each hi-half; one store per row.
    #pragma unroll
    for (int s = 0; s < 2; ++s)
        #pragma unroll
        for (int r = 0; r < 16; ++r) {
            float v = sums[s][r];
            v += __shfl_xor(v, 1);
            v += __shfl_xor(v, 2);
            v += __shfl_xor(v, 4);
            v += __shfl_xor(v, 8);
            v += __shfl_xor(v, 16);
            if (c31 == 0) {
                const int row = wrow + s * 32 + (r & 3) + 8 * (r >> 2) + 4 * hi;
                psums[blockIdx.y * N + row] = v;
            }
        }
}

// K3a: per-row loss = log(sum of partials) - pos; block-reduce; atomic into acc0.
__global__ __launch_bounds__(1024) void k_rowloss(const float* __restrict__ psums,
                                                  const float* __restrict__ pos,
                                                  float* __restrict__ acc0) {
    const int row = blockIdx.x * 1024 + threadIdx.x;
    float t = 0.0f;
    #pragma unroll
    for (int s = 0; s < COL_SPLITS; ++s) t += psums[s * N + row];
    float loss = __logf(t) - pos[row];
    #pragma unroll
    for (int m = 32; m >= 1; m >>= 1) loss += __shfl_xor(loss, m);
    __shared__ float p[16];
    if ((threadIdx.x & 63) == 0) p[threadIdx.x >> 6] = loss;
    __syncthreads();
    if (threadIdx.x == 0) {
        float s = 0.0f;
        #pragma unroll
        for (int w = 0; w < 16; ++w) s += p[w];
        atomicAdd(acc0, s);
    }
}

// K3b: mean.
__global__ void k_final(const float* __restrict__ acc0, float* __restrict__ out) {
    out[0] = acc0[0] * (1.0f / N);
}

extern "C" void kernel_launch(void* const* d_in, const int* in_sizes, int n_in,
                              void* d_out, int out_size, void* d_ws, size_t ws_size,
                              hipStream_t stream) {
    const float* x = (const float*)d_in[0];
    float* wsf   = (float*)d_ws;
    float* pos   = wsf + OFF_POS;
    float* psums = wsf + OFF_PSUMS;
    float* acc0  = wsf + OFF_ACC;
    unsigned short* z = (unsigned short*)((char*)d_ws + OFF_Z_BYTES);

    k_normalize<<<N / 4, 256, 0, stream>>>(x, z, acc0);
    dim3 g2(N / BLOCK_ROWS, COL_SPLITS);  // (32, 16) = 512 blocks -> 2/CU
    k_simloss<<<g2, 256, 0, stream>>>(z, psums, pos);
    k_rowloss<<<N / 1024, 1024, 0, stream>>>(psums, pos, acc0);
    k_final<<<1, 1, 0, stream>>>(acc0, (float*)d_out);
}